// Round 2
// baseline (60.974 us; speedup 1.0000x reference)
//
#include <hip/hip_runtime.h>

#define VOCAB 32000
#define EDIM  128
#define QN    32
#define DN    256
#define DTILE 64
#define DS    4          // doc splits per batch
#define NK    11
#define LDSP  (EDIM + 4) // 132 floats: lane stride 132 = 4 banks -> 2 lanes/bank (free)

// ---------------- inv-norm precompute: one wave per vocab row ----------------
__global__ __launch_bounds__(256) void invnorm_kernel(const float* __restrict__ emb,
                                                      float* __restrict__ invn) {
    int lane = threadIdx.x & 63;
    int row  = blockIdx.x * 4 + (threadIdx.x >> 6);
    if (row >= VOCAB) return;
    const float2* p = (const float2*)(emb + (size_t)row * EDIM);
    float2 v = p[lane];
    float s = v.x * v.x + v.y * v.y;
    #pragma unroll
    for (int off = 32; off; off >>= 1) s += __shfl_xor(s, off);
    if (lane == 0) invn[row] = 1.0f / sqrtf(s);
}

#define DOT4(acc, a, v)                                                        \
    acc = fmaf((a).x, (v).x, acc);                                             \
    acc = fmaf((a).y, (v).y, acc);                                             \
    acc = fmaf((a).z, (v).z, acc);                                             \
    acc = fmaf((a).w, (v).w, acc);

// ---------------- partial: one block per (batch, doc-quarter) ----------------
// 128 threads: qg = tid>>4 (8 groups x 4 q-rows), dg = tid&15 (4 strided d-rows)
__global__ __launch_bounds__(128) void knrm_partial(const int* __restrict__ qtok,
                                                    const int* __restrict__ dtok,
                                                    const float* __restrict__ emb,
                                                    const float* __restrict__ invn,
                                                    float* __restrict__ part) {
    __shared__ __align__(16) float qn[QN][LDSP];
    __shared__ __align__(16) float dt[DTILE][LDSP];
    __shared__ float dscale[DTILE];

    const float MU[NK] = {1.0f, 0.9f, 0.7f, 0.5f, 0.3f, 0.1f,
                          -0.1f, -0.3f, -0.5f, -0.7f, -0.9f};
    const float CC[NK] = {-5.0e7f, -50.0f, -50.0f, -50.0f, -50.0f, -50.0f,
                          -50.0f, -50.0f, -50.0f, -50.0f, -50.0f};
    const float INV_SQRT_2PI = 0.3989422804014327f;

    int b   = blockIdx.x >> 2;        // batch
    int ds  = blockIdx.x & 3;         // doc quarter
    int tid = threadIdx.x;
    const int* qt  = qtok + b * QN;
    const int* dtk = dtok + b * DN + ds * DTILE;

    // ---- stage normalized queries: 32 rows, 4 threads/row, 8 float4 each ----
    {
        int r = tid & 31, c = tid >> 5;        // c in [0,4)
        int tok = qt[r];
        float inv = invn[tok];
        const float4* src = (const float4*)(emb + (size_t)tok * EDIM);
        float4* dst = (float4*)&qn[r][0];
        #pragma unroll
        for (int j = 0; j < 8; ++j) {
            float4 v = src[c * 8 + j];
            v.x *= inv; v.y *= inv; v.z *= inv; v.w *= inv;
            dst[c * 8 + j] = v;
        }
    }
    // ---- stage normalized doc tile: 64 rows, 2 threads/row, 16 float4 each ----
    {
        int r = tid & 63, c = tid >> 6;        // c in [0,2)
        int tok = dtk[r];
        float inv = invn[tok];
        const float4* src = (const float4*)(emb + (size_t)tok * EDIM);
        float4* dst = (float4*)&dt[r][0];
        #pragma unroll
        for (int j = 0; j < 16; ++j) {
            float4 v = src[c * 16 + j];
            v.x *= inv; v.y *= inv; v.z *= inv; v.w *= inv;
            dst[c * 16 + j] = v;
        }
        if (c == 0) dscale[r] = (tok > 0) ? INV_SQRT_2PI : 0.0f;
    }
    __syncthreads();

    int qg = tid >> 4;   // 0..7  -> q rows 4qg..4qg+3
    int dg = tid & 15;   // 0..15 -> d rows dg, dg+16, dg+32, dg+48 (strided!)

    const float4* q0 = (const float4*)&qn[qg * 4 + 0][0];
    const float4* q1 = (const float4*)&qn[qg * 4 + 1][0];
    const float4* q2 = (const float4*)&qn[qg * 4 + 2][0];
    const float4* q3 = (const float4*)&qn[qg * 4 + 3][0];
    const float4* d0 = (const float4*)&dt[dg +  0][0];
    const float4* d1 = (const float4*)&dt[dg + 16][0];
    const float4* d2 = (const float4*)&dt[dg + 32][0];
    const float4* d3 = (const float4*)&dt[dg + 48][0];

    float dot[4][4];
    #pragma unroll
    for (int qq = 0; qq < 4; ++qq)
        #pragma unroll
        for (int i = 0; i < 4; ++i) dot[qq][i] = 0.0f;

    #pragma unroll 4
    for (int e = 0; e < EDIM / 4; ++e) {
        float4 a0 = q0[e], a1 = q1[e], a2 = q2[e], a3 = q3[e];
        float4 v0 = d0[e], v1 = d1[e], v2 = d2[e], v3 = d3[e];
        DOT4(dot[0][0], a0, v0); DOT4(dot[0][1], a0, v1);
        DOT4(dot[0][2], a0, v2); DOT4(dot[0][3], a0, v3);
        DOT4(dot[1][0], a1, v0); DOT4(dot[1][1], a1, v1);
        DOT4(dot[1][2], a1, v2); DOT4(dot[1][3], a1, v3);
        DOT4(dot[2][0], a2, v0); DOT4(dot[2][1], a2, v1);
        DOT4(dot[2][2], a2, v2); DOT4(dot[2][3], a2, v3);
        DOT4(dot[3][0], a3, v0); DOT4(dot[3][1], a3, v1);
        DOT4(dot[3][2], a3, v2); DOT4(dot[3][3], a3, v3);
    }

    // ---- 11 Gaussian kernels; d-mask & 1/sqrt(2pi) folded into dscale ----
    float kacc[4][NK];
    #pragma unroll
    for (int qq = 0; qq < 4; ++qq)
        #pragma unroll
        for (int k = 0; k < NK; ++k) kacc[qq][k] = 0.0f;

    #pragma unroll
    for (int i = 0; i < 4; ++i) {
        float sc = dscale[dg + 16 * i];
        #pragma unroll
        for (int qq = 0; qq < 4; ++qq) {
            float t = dot[qq][i];
            #pragma unroll
            for (int k = 0; k < NK; ++k) {
                float u = t - MU[k];
                kacc[qq][k] = fmaf(__expf(u * u * CC[k]), sc, kacc[qq][k]);
            }
        }
    }

    // ---- reduce over the 16 dg lanes (within wave) ----
    #pragma unroll
    for (int off = 1; off < 16; off <<= 1)
        #pragma unroll
        for (int qq = 0; qq < 4; ++qq)
            #pragma unroll
            for (int k = 0; k < NK; ++k)
                kacc[qq][k] += __shfl_xor(kacc[qq][k], off);

    if (dg == 0) {
        float* dst = part + (size_t)blockIdx.x * (QN * NK) + qg * 4 * NK;
        #pragma unroll
        for (int qq = 0; qq < 4; ++qq)
            #pragma unroll
            for (int k = 0; k < NK; ++k)
                dst[qq * NK + k] = kacc[qq][k];
    }
}

// ---------------- final: one block per batch, sum 4 partials + log-pool ----------------
__global__ __launch_bounds__(128) void knrm_reduce(const int* __restrict__ qtok,
                                                   const float* __restrict__ part,
                                                   const float* __restrict__ fcw,
                                                   float* __restrict__ out) {
    __shared__ float fw[NK];
    __shared__ float red[2];
    int b = blockIdx.x, tid = threadIdx.x;
    if (tid < NK) fw[tid] = fcw[tid];
    __syncthreads();

    const float* p = part + (size_t)b * DS * (QN * NK);
    float sum = 0.0f;
    for (int i = tid; i < QN * NK; i += 128) {
        int q = i / NK, k = i - q * NK;
        float v = p[i] + p[QN * NK + i] + p[2 * QN * NK + i] + p[3 * QN * NK + i];
        float m = (qtok[b * QN + q] > 0) ? 1.0f : 0.0f;
        sum += m * fw[k] * __logf(fmaxf(v, 1e-10f));
    }
    #pragma unroll
    for (int off = 32; off; off >>= 1) sum += __shfl_xor(sum, off);
    if ((tid & 63) == 0) red[tid >> 6] = sum;
    __syncthreads();
    if (tid == 0) out[b] = red[0] + red[1];
}

extern "C" void kernel_launch(void* const* d_in, const int* in_sizes, int n_in,
                              void* d_out, int out_size, void* d_ws, size_t ws_size,
                              hipStream_t stream) {
    const int*   qtok = (const int*)d_in[0];
    const int*   dtok = (const int*)d_in[1];
    const float* emb  = (const float*)d_in[2];
    const float* fcw  = (const float*)d_in[3];
    float* out  = (float*)d_out;
    float* invn = (float*)d_ws;                 // 32000 floats = 128 KB
    float* part = (float*)d_ws + VOCAB;         // 2048 * 352 floats = 2.88 MB

    invnorm_kernel<<<(VOCAB + 3) / 4, 256, 0, stream>>>(emb, invn);

    int B = in_sizes[0] / QN;                   // 512
    knrm_partial<<<B * DS, 128, 0, stream>>>(qtok, dtok, emb, invn, part);
    knrm_reduce<<<B, 128, 0, stream>>>(qtok, part, fcw, out);
}

// Round 3
// 31.537 us; speedup vs baseline: 1.9334x; 1.9334x over previous
//
#include <hip/hip_runtime.h>

#define VOCAB 32000
#define EDIM  128
#define QN    32
#define DN    256
#define NK    11

typedef __attribute__((ext_vector_type(8))) short bf16x8;
typedef __attribute__((ext_vector_type(4))) float f32x4;

// RNE float -> bf16 (inputs are finite normals; no NaN handling needed)
static __device__ inline unsigned short f2bf(float f) {
    unsigned u = __float_as_uint(f);
    return (unsigned short)((u + 0x7fff + ((u >> 16) & 1)) >> 16);
}

// ---------------- pre-pass: L2-normalize rows + convert to bf16 table ----------------
__global__ __launch_bounds__(256) void norm_bf16_kernel(const float* __restrict__ emb,
                                                        unsigned int* __restrict__ nbf) {
    int lane = threadIdx.x & 63;
    int row  = blockIdx.x * 4 + (threadIdx.x >> 6);
    if (row >= VOCAB) return;
    const float2* p = (const float2*)(emb + (size_t)row * EDIM);
    float2 v = p[lane];
    float s = v.x * v.x + v.y * v.y;
    #pragma unroll
    for (int off = 32; off; off >>= 1) s += __shfl_xor(s, off);
    float inv = 1.0f / sqrtf(s);
    unsigned int packed = ((unsigned)f2bf(v.y * inv) << 16) | f2bf(v.x * inv);
    nbf[(size_t)row * (EDIM / 2) + lane] = packed;   // 2 bf16 per lane, coalesced
}

// ---------------- main: one block (8 waves) per batch ----------------
// wave w: q-tile (w&1), d-tiles (w>>1)*4 .. +4.  Fragments gathered from global.
__global__ __launch_bounds__(512, 4) void knrm_mfma(const int* __restrict__ qtok,
                                                    const int* __restrict__ dtok,
                                                    const unsigned short* __restrict__ nbf,
                                                    const float* __restrict__ fcw,
                                                    float* __restrict__ out) {
    __shared__ int   qtokS[QN];
    __shared__ int   dtokS[DN];
    __shared__ float part[8][QN][NK + 1];
    __shared__ float redS[8];

    const float MU[NK] = {1.0f, 0.9f, 0.7f, 0.5f, 0.3f, 0.1f,
                          -0.1f, -0.3f, -0.5f, -0.7f, -0.9f};
    const float INV_SQRT_2PI = 0.3989422804014327f;

    int b = blockIdx.x, tid = threadIdx.x;
    if (tid < DN) dtokS[tid] = dtok[b * DN + tid];
    else if (tid < DN + QN) qtokS[tid - DN] = qtok[b * QN + tid - DN];
    __syncthreads();

    int w = tid >> 6, lane = tid & 63;
    int qtile = w & 1, dg = w >> 1;
    int lr = lane & 15, lg = lane >> 4;

    // ---- A fragments for this wave's q-tile: lane holds Q[qtile*16+lr][k-slice] ----
    bf16x8 A[4];
    {
        int tok = qtokS[qtile * 16 + lr];
        const unsigned short* base = nbf + (size_t)tok * EDIM + lg * 8;
        #pragma unroll
        for (int s = 0; s < 4; ++s) A[s] = *(const bf16x8*)(base + s * 32);
    }
    // q tokens for this lane's C-rows (C/D layout: row = lg*4 + r, col = lr)
    int qt[4];
    #pragma unroll
    for (int r = 0; r < 4; ++r) qt[r] = qtokS[qtile * 16 + lg * 4 + r];

    float kacc[4][NK];
    #pragma unroll
    for (int r = 0; r < 4; ++r)
        #pragma unroll
        for (int k = 0; k < NK; ++k) kacc[r][k] = 0.0f;

    int t0 = dg * 4;

    // prefetch first B tile: lane holds Dn[t*16+lr][k-slice]
    int tdc = dtokS[t0 * 16 + lr];
    bf16x8 Bc0, Bc1, Bc2, Bc3;
    {
        const unsigned short* base = nbf + (size_t)tdc * EDIM + lg * 8;
        Bc0 = *(const bf16x8*)(base);
        Bc1 = *(const bf16x8*)(base + 32);
        Bc2 = *(const bf16x8*)(base + 64);
        Bc3 = *(const bf16x8*)(base + 96);
    }

    #pragma unroll
    for (int i = 0; i < 4; ++i) {
        // issue next tile's loads early (in flight during mfma+eval)
        int tdn = 0;
        bf16x8 Bn0, Bn1, Bn2, Bn3;
        if (i < 3) {
            tdn = dtokS[(t0 + i + 1) * 16 + lr];
            const unsigned short* base = nbf + (size_t)tdn * EDIM + lg * 8;
            Bn0 = *(const bf16x8*)(base);
            Bn1 = *(const bf16x8*)(base + 32);
            Bn2 = *(const bf16x8*)(base + 64);
            Bn3 = *(const bf16x8*)(base + 96);
        }

        // ---- tm tile: chained K accumulation ----
        f32x4 acc = {0.0f, 0.0f, 0.0f, 0.0f};
        acc = __builtin_amdgcn_mfma_f32_16x16x32_bf16(A[0], Bc0, acc, 0, 0, 0);
        acc = __builtin_amdgcn_mfma_f32_16x16x32_bf16(A[1], Bc1, acc, 0, 0, 0);
        acc = __builtin_amdgcn_mfma_f32_16x16x32_bf16(A[2], Bc2, acc, 0, 0, 0);
        acc = __builtin_amdgcn_mfma_f32_16x16x32_bf16(A[3], Bc3, acc, 0, 0, 0);

        // ---- kernel eval on registers; K0 via exact integer match ----
        float sc = (tdc > 0) ? INV_SQRT_2PI : 0.0f;
        #pragma unroll
        for (int r = 0; r < 4; ++r) {
            float t = acc[r];
            kacc[r][0] += (tdc > 0 && tdc == qt[r]) ? INV_SQRT_2PI : 0.0f;
            #pragma unroll
            for (int k = 1; k < NK; ++k) {
                float u = t - MU[k];
                kacc[r][k] = fmaf(__expf(-50.0f * u * u), sc, kacc[r][k]);
            }
        }

        tdc = tdn;
        Bc0 = Bn0; Bc1 = Bn1; Bc2 = Bn2; Bc3 = Bn3;
    }

    // ---- reduce over the 16 doc-columns (lanes differing in lr) ----
    #pragma unroll
    for (int off = 1; off < 16; off <<= 1)
        #pragma unroll
        for (int r = 0; r < 4; ++r)
            #pragma unroll
            for (int k = 0; k < NK; ++k)
                kacc[r][k] += __shfl_xor(kacc[r][k], off);

    if (lr == 0) {
        #pragma unroll
        for (int r = 0; r < 4; ++r)
            #pragma unroll
            for (int k = 0; k < NK; ++k)
                part[w][qtile * 16 + lg * 4 + r][k] = kacc[r][k];
    }
    __syncthreads();

    // ---- combine 4 d-range partials, log-pool, weighted sum ----
    float total = 0.0f;
    for (int i = tid; i < QN * NK; i += 512) {
        int q = i / NK, k = i - q * NK;
        int par = q >> 4;
        float v = part[par][q][k] + part[par + 2][q][k] +
                  part[par + 4][q][k] + part[par + 6][q][k];
        float m = (qtokS[q] > 0) ? 1.0f : 0.0f;
        total += m * fcw[k] * __logf(fmaxf(v, 1e-10f));
    }
    #pragma unroll
    for (int off = 32; off; off >>= 1) total += __shfl_xor(total, off);
    if (lane == 0) redS[w] = total;
    __syncthreads();
    if (tid == 0) {
        float s = 0.0f;
        #pragma unroll
        for (int i = 0; i < 8; ++i) s += redS[i];
        out[b] = s;
    }
}

extern "C" void kernel_launch(void* const* d_in, const int* in_sizes, int n_in,
                              void* d_out, int out_size, void* d_ws, size_t ws_size,
                              hipStream_t stream) {
    const int*   qtok = (const int*)d_in[0];
    const int*   dtok = (const int*)d_in[1];
    const float* emb  = (const float*)d_in[2];
    const float* fcw  = (const float*)d_in[3];
    float* out = (float*)d_out;
    unsigned int* nbf = (unsigned int*)d_ws;   // 32000*128 bf16 = 8.192 MB

    norm_bf16_kernel<<<VOCAB / 4, 256, 0, stream>>>(emb, nbf);

    int B = in_sizes[0] / QN;                  // 512
    knrm_mfma<<<B, 512, 0, stream>>>(qtok, dtok, (const unsigned short*)nbf, fcw, out);
}

// Round 5
// 31.535 us; speedup vs baseline: 1.9335x; 1.0001x over previous
//
#include <hip/hip_runtime.h>

#define VOCAB 32000
#define EDIM  128
#define QN    32
#define DN    256
#define NK    11

typedef __attribute__((ext_vector_type(8))) short bf16x8;
typedef __attribute__((ext_vector_type(4))) float f32x4;

#define EXP2F(x) __builtin_amdgcn_exp2f(x)

// RNE float -> bf16
static __device__ inline unsigned short f2bf(float f) {
    unsigned u = __float_as_uint(f);
    return (unsigned short)((u + 0x7fff + ((u >> 16) & 1)) >> 16);
}

// ---------------- pre-pass: L2-normalize rows + convert to bf16 table ----------------
__global__ __launch_bounds__(256) void norm_bf16_kernel(const float* __restrict__ emb,
                                                        unsigned int* __restrict__ nbf) {
    int lane = threadIdx.x & 63;
    int row  = blockIdx.x * 4 + (threadIdx.x >> 6);
    const float2* p = (const float2*)(emb + (size_t)row * EDIM);
    float2 v = p[lane];
    float s = v.x * v.x + v.y * v.y;
    #pragma unroll
    for (int off = 32; off; off >>= 1) s += __shfl_xor(s, off);
    float inv = 1.0f / sqrtf(s);
    unsigned int packed = ((unsigned)f2bf(v.y * inv) << 16) | f2bf(v.x * inv);
    nbf[(size_t)row * (EDIM / 2) + lane] = packed;
}

// ---- DPP 16-lane sum: quad xor1, xor2, then row_ror:4, row_ror:8 (all lanes get sum) ----
template <int CTRL>
static __device__ inline float dpp_add(float x) {
    int y = __builtin_amdgcn_update_dpp(0, __float_as_int(x), CTRL, 0xF, 0xF, true);
    return x + __int_as_float(y);
}
static __device__ inline float sum16(float x) {
    x = dpp_add<0xB1>(x);    // quad_perm [1,0,3,2]  : xor 1
    x = dpp_add<0x4E>(x);    // quad_perm [2,3,0,1]  : xor 2
    x = dpp_add<0x124>(x);   // row_ror:4
    x = dpp_add<0x128>(x);   // row_ror:8
    return x;
}

// ---------------- main: 4 independent waves per block, no barriers ----------------
// task = b*8 + qtile*4 + dspan ; wave computes tm for 16 q-rows x 64 docs via MFMA,
// evaluates kernels with the exp-chain, DPP-reduces, writes [16][NK] partial.
__global__ __launch_bounds__(256, 4) void knrm_mfma(const int* __restrict__ qtok,
                                                    const int* __restrict__ dtok,
                                                    const unsigned short* __restrict__ nbf,
                                                    float* __restrict__ part) {
    const float INV_SQRT_2PI = 0.3989422804014327f;
    // chain constants: c_m = exp(20*mu_m - 2), mu_m = 0.9 - 0.2(m-1)
    const float CCH[9] = {8886110.5f, 162754.797f, 2980.95799f, 54.5981500f, 1.0f,
                          0.0183156389f, 3.35462628e-4f, 6.14421235e-6f, 1.12535175e-7f};

    int task = blockIdx.x * 4 + (threadIdx.x >> 6);
    int lane = threadIdx.x & 63;
    int b     = task >> 3;
    int qtile = (task >> 2) & 1;
    int dspan = task & 3;
    int lr = lane & 15, lg = lane >> 4;

    const int* qt_p = qtok + b * QN + qtile * 16;
    const int* dt_p = dtok + b * DN + dspan * 64;

    // ---- A fragments: lane holds Q[lr][k-slice lg*8 + s*32] ----
    bf16x8 A0, A1, A2, A3;
    {
        int tok = qt_p[lr];
        const unsigned short* base = nbf + (size_t)tok * EDIM + lg * 8;
        A0 = *(const bf16x8*)(base);
        A1 = *(const bf16x8*)(base + 32);
        A2 = *(const bf16x8*)(base + 64);
        A3 = *(const bf16x8*)(base + 96);
    }
    // q tokens for this lane's C-rows (row = lg*4 + r, col = lr)
    int qtr[4];
    #pragma unroll
    for (int r = 0; r < 4; ++r) qtr[r] = qt_p[lg * 4 + r];

    float kacc[4][NK];
    #pragma unroll
    for (int r = 0; r < 4; ++r)
        #pragma unroll
        for (int k = 0; k < NK; ++k) kacc[r][k] = 0.0f;

    // ---- pipeline: token 2 ahead, B-tile 1 ahead ----
    int tcur = dt_p[lr];
    int tnxt = dt_p[16 + lr];
    bf16x8 B0, B1, B2, B3;
    {
        const unsigned short* base = nbf + (size_t)tcur * EDIM + lg * 8;
        B0 = *(const bf16x8*)(base);
        B1 = *(const bf16x8*)(base + 32);
        B2 = *(const bf16x8*)(base + 64);
        B3 = *(const bf16x8*)(base + 96);
    }

    #pragma unroll
    for (int i = 0; i < 4; ++i) {
        int tnn = 0;
        if (i < 2) tnn = dt_p[(i + 2) * 16 + lr];
        bf16x8 N0, N1, N2, N3;
        if (i < 3) {
            const unsigned short* base = nbf + (size_t)tnxt * EDIM + lg * 8;
            N0 = *(const bf16x8*)(base);
            N1 = *(const bf16x8*)(base + 32);
            N2 = *(const bf16x8*)(base + 64);
            N3 = *(const bf16x8*)(base + 96);
        }

        f32x4 acc = {0.0f, 0.0f, 0.0f, 0.0f};
        acc = __builtin_amdgcn_mfma_f32_16x16x32_bf16(A0, B0, acc, 0, 0, 0);
        acc = __builtin_amdgcn_mfma_f32_16x16x32_bf16(A1, B1, acc, 0, 0, 0);
        acc = __builtin_amdgcn_mfma_f32_16x16x32_bf16(A2, B2, acc, 0, 0, 0);
        acc = __builtin_amdgcn_mfma_f32_16x16x32_bf16(A3, B3, acc, 0, 0, 0);

        // ---- kernel eval: exp-chain over |t|, sign via dual scales ----
        float sc = (tcur > 0) ? INV_SQRT_2PI : 0.0f;
        #pragma unroll
        for (int r = 0; r < 4; ++r) {
            float t = acc[r];
            // K0: exact integer token match (sigma=1e-4 kernel)
            kacc[r][0] += (tcur == qtr[r]) ? sc : 0.0f;
            float s   = fabsf(t);
            float scP = (t >= 0.0f) ? sc : 0.0f;
            float scN = sc - scP;
            float d   = s - 0.9f;
            float g   = EXP2F(d * d * -72.1347520f);   // exp(-50(s-0.9)^2)
            float E   = EXP2F(s * -28.8539008f);       // exp(-20s)
            #pragma unroll
            for (int m = 1; m <= 10; ++m) {
                kacc[r][m]      = fmaf(g, scP, kacc[r][m]);
                kacc[r][11 - m] = fmaf(g, scN, kacc[r][11 - m]);
                if (m < 10) g = g * E * CCH[m - 1];
            }
        }

        tcur = tnxt; tnxt = tnn;
        B0 = N0; B1 = N1; B2 = N2; B3 = N3;
    }

    // ---- DPP reduce over 16 doc-columns; write partial [16 rows][NK] ----
    #pragma unroll
    for (int r = 0; r < 4; ++r)
        #pragma unroll
        for (int k = 0; k < NK; ++k) kacc[r][k] = sum16(kacc[r][k]);

    if (lr == 0) {
        float* dst = part + ((size_t)task * 16 + lg * 4) * NK;
        #pragma unroll
        for (int r = 0; r < 4; ++r)
            #pragma unroll
            for (int k = 0; k < NK; ++k)
                dst[r * NK + k] = kacc[r][k];
    }
}

// ---------------- final: one block per batch, sum 4 dspans + log-pool ----------------
__global__ __launch_bounds__(128) void knrm_reduce(const int* __restrict__ qtok,
                                                   const float* __restrict__ part,
                                                   const float* __restrict__ fcw,
                                                   float* __restrict__ out) {
    __shared__ float red[2];
    int b = blockIdx.x, tid = threadIdx.x;
    const float* p = part + (size_t)b * 8 * 16 * NK;

    float sum = 0.0f;
    for (int i = tid; i < QN * NK; i += 128) {
        int q = i / NK, k = i - q * NK;
        int qt = q >> 4, row = q & 15;
        const float* pb = p + (qt * 4 * 16 + row) * NK + k;
        float v = pb[0] + pb[16 * NK] + pb[32 * NK] + pb[48 * NK];
        float m = (qtok[b * QN + q] > 0) ? 1.0f : 0.0f;
        sum += m * fcw[k] * __logf(fmaxf(v, 1e-10f));
    }
    #pragma unroll
    for (int off = 32; off; off >>= 1) sum += __shfl_xor(sum, off);
    if ((tid & 63) == 0) red[tid >> 6] = sum;
    __syncthreads();
    if (tid == 0) out[b] = red[0] + red[1];
}

extern "C" void kernel_launch(void* const* d_in, const int* in_sizes, int n_in,
                              void* d_out, int out_size, void* d_ws, size_t ws_size,
                              hipStream_t stream) {
    const int*   qtok = (const int*)d_in[0];
    const int*   dtok = (const int*)d_in[1];
    const float* emb  = (const float*)d_in[2];
    const float* fcw  = (const float*)d_in[3];
    float* out = (float*)d_out;
    unsigned int* nbf = (unsigned int*)d_ws;                    // 8.192 MB bf16 table
    float* part = (float*)((char*)d_ws + (size_t)VOCAB * EDIM * 2); // 4096*176 floats

    norm_bf16_kernel<<<VOCAB / 4, 256, 0, stream>>>(emb, nbf);

    int B = in_sizes[0] / QN;                                   // 512
    knrm_mfma<<<B * 2, 256, 0, stream>>>(qtok, dtok, (const unsigned short*)nbf, part);
    knrm_reduce<<<B, 128, 0, stream>>>(qtok, part, fcw, out);
}